// Round 3
// baseline (186.763 us; speedup 1.0000x reference)
//
#include <hip/hip_runtime.h>
#include <hip/hip_bf16.h>

// MaskFiller scatter:
//   out[b, keep_ids[b,k], :] = inputs[b,k,:]
//   out[b, mask_ids[b,m], :] = mask_embedding[:]
// B=8, K=4096, M=4096, L=8192, D=512 (fp32).
// keep+mask ids partition [0,L) per batch -> every row written exactly once,
// no zero-init, no atomics.
//
// R2: same persistent grid-stride design as R1, but use clang ext_vector
// float4 (native vector) so __builtin_nontemporal_* accepts the pointer.

typedef float f4 __attribute__((ext_vector_type(4)));

constexpr int B  = 8;
constexpr int K  = 4096;
constexpr int M  = 4096;
constexpr int L  = K + M;   // 8192
constexpr int D  = 512;
constexpr int D4 = D / 4;   // 128 f4 per row

constexpr int THREADS = 256;
constexpr int ROWS_PER_ITER = THREADS / D4;  // 2 rows per block-iteration
constexpr int GRID = 2048;                   // 8 blocks/CU on 256 CUs

__global__ __launch_bounds__(THREADS)
void MaskFiller_scatter_kernel(const f4* __restrict__ inputs,
                               const int* __restrict__ mask_ids,
                               const int* __restrict__ keep_ids,
                               const f4* __restrict__ emb,
                               f4* __restrict__ out) {
    const int d4  = threadIdx.x & (D4 - 1);   // 0..127 within row
    const int sub = threadIdx.x >> 7;         // which row of the pair
    const f4 ev = emb[d4];                    // 2 KB, L1-resident broadcast

    const int stride = GRID * ROWS_PER_ITER;  // 4096 rows per sweep
    int row = blockIdx.x * ROWS_PER_ITER + sub;

    #pragma unroll 4
    for (; row < B * L; row += stride) {
        const int b = row >> 13;          // row / L  (L = 8192)
        const int r = row & (L - 1);      // row % L
        int dst;
        f4 v;
        if (r < K) {
            const int src = (b << 12) + r;            // b*K + r
            dst = keep_ids[src];
            v   = __builtin_nontemporal_load(&inputs[((size_t)src << 7) + d4]);
        } else {
            dst = mask_ids[(b << 12) + (r - K)];      // b*M + (r-K)
            v   = ev;
        }
        __builtin_nontemporal_store(v, &out[(((size_t)(b << 13) + dst) << 7) + d4]);
    }
}

extern "C" void kernel_launch(void* const* d_in, const int* in_sizes, int n_in,
                              void* d_out, int out_size, void* d_ws, size_t ws_size,
                              hipStream_t stream) {
    const f4*  inputs   = (const f4*)d_in[0];
    const int* mask_ids = (const int*)d_in[1];
    const int* keep_ids = (const int*)d_in[2];
    const f4*  emb      = (const f4*)d_in[3];
    // d_in[4] is `axis` (-2), unused.
    f4* out = (f4*)d_out;

    MaskFiller_scatter_kernel<<<dim3(GRID), dim3(THREADS), 0, stream>>>(
        inputs, mask_ids, keep_ids, emb, out);
}